// Round 4
// baseline (1149.532 us; speedup 1.0000x reference)
//
#include <hip/hip_runtime.h>
#include <hip/hip_bf16.h>
#include <stdint.h>

#define NTOK  4096
#define TOPK  2
#define NEXP  8
#define HID   1024
#define INTER 2048
#define NPAIR (NTOK*TOPK)

typedef __attribute__((ext_vector_type(8))) short short8;
typedef __attribute__((ext_vector_type(4))) float floatx4;

// ---------------- ws layout (bytes) ----------------
// ctrl @0: counts(8 int)@0, offsets@64, fill@128, flags@192 (6 int)
#define O_PERMTOK 4096ull
#define O_PERMW   (O_PERMTOK + (size_t)NPAIR*4)            // float[NPAIR]
#define O_X       (1ull<<20)                                // bf16 [NPAIR][HID]    16 MB
#define O_WG      (O_X  + (size_t)NPAIR*HID*2)              // bf16 [E][INTER][HID] 32 MB
#define O_WU      (O_WG + (size_t)NEXP*INTER*HID*2)
#define O_WD      (O_WU + (size_t)NEXP*INTER*HID*2)         // bf16 [E][HID][INTER] 32 MB
#define O_HBUF    (O_WD + (size_t)NEXP*HID*INTER*2)         // bf16 [NPAIR][INTER]  32 MB
#define WS_NEEDED (O_HBUF + (size_t)NPAIR*INTER*2)

static __device__ __forceinline__ unsigned short f32_to_bf16_rne(float f) {
    union { float f; uint32_t u; } v; v.f = f;
    uint32_t b = v.u + 0x7fffu + ((v.u >> 16) & 1u);
    return (unsigned short)(b >> 16);
}
static __device__ __forceinline__ float bf16_to_f32(unsigned short u) {
    union { uint32_t i; float f; } cv; cv.i = ((uint32_t)u) << 16;
    return cv.f;
}

// ---------------- dtype probes (per tensor) ----------------
// flags[0..4] = 1 if {tokens, ew, gw, uw, dw} is fp32, 0 if bf16
// flags[5]    = 1 if expert_indices is int64, 0 if int32
__global__ void k_probe(const void* __restrict__ tok, const void* __restrict__ ew,
                        const void* __restrict__ gw,  const void* __restrict__ uw,
                        const void* __restrict__ dw,  const void* __restrict__ eidx,
                        int* __restrict__ flags) {
    int lane = threadIdx.x;  // 64
    const void* ptrs[5] = { tok, ew, gw, uw, dw };
    for (int t = 0; t < 5; ++t) {
        const unsigned short* p = (const unsigned short*)ptrs[t];
        float v = bf16_to_f32(p[lane * 2]);
        unsigned long long m = __ballot(!(fabsf(v) < 1000.0f));
        if (lane == 0) flags[t] = (m != 0ull) ? 1 : 0;
    }
    const int* ix = (const int*)eidx;
    unsigned long long mi = __ballot(ix[lane * 2 + 1] != 0);
    if (lane == 0) flags[5] = (mi == 0ull) ? 1 : 0;
}

// ---------------- routing ----------------
__global__ void k_route_count(const int* __restrict__ idx, int* __restrict__ counts,
                              const int* __restrict__ flags) {
    int i64 = flags[5];
    int p = blockIdx.x * 256 + threadIdx.x;
    if (p < NPAIR) atomicAdd(&counts[idx[p << i64]], 1);
}

__global__ void k_route_scan(const int* __restrict__ counts, int* __restrict__ offsets,
                             int* __restrict__ fill) {
    if (threadIdx.x == 0) {
        int acc = 0;
        for (int e = 0; e < NEXP; ++e) { offsets[e] = acc; acc += counts[e]; fill[e] = 0; }
    }
}

__global__ void k_route_fill(const int* __restrict__ idx, const void* __restrict__ ew,
                             const int* __restrict__ offsets, int* __restrict__ fill,
                             int* __restrict__ perm_tok, float* __restrict__ perm_w,
                             const int* __restrict__ flags) {
    int ewf = flags[1], i64 = flags[5];
    int p = blockIdx.x * 256 + threadIdx.x;
    if (p < NPAIR) {
        int e = idx[p << i64];
        int pos = offsets[e] + atomicAdd(&fill[e], 1);
        perm_tok[pos] = p >> 1;
        perm_w[pos]   = ewf ? ((const float*)ew)[p]
                            : bf16_to_f32(((const unsigned short*)ew)[p]);
    }
}

// gather packed token rows -> bf16 X
__global__ void k_gather(const void* __restrict__ tokens, const int* __restrict__ perm_tok,
                         unsigned short* __restrict__ X, const int* __restrict__ flags) {
    int f = flags[0];
    int pos = blockIdx.x;
    int tok = perm_tok[pos];
    ushort4* d = (ushort4*)(X + (size_t)pos * HID);
    if (f) {
        float4 v = *(const float4*)((const float*)tokens + (size_t)tok * HID + threadIdx.x * 4);
        ushort4 o;
        o.x = f32_to_bf16_rne(v.x); o.y = f32_to_bf16_rne(v.y);
        o.z = f32_to_bf16_rne(v.z); o.w = f32_to_bf16_rne(v.w);
        d[threadIdx.x] = o;
    } else {
        d[threadIdx.x] = ((const ushort4*)((const unsigned short*)tokens + (size_t)tok * HID))[threadIdx.x];
    }
}

// transpose [R][C] -> bf16 [C][R] per expert (blockIdx.z), dual input dtype
__global__ void k_transpose(const void* __restrict__ src,
                            unsigned short* __restrict__ dst, int R, int C,
                            const int* __restrict__ flags, int flagIdx) {
    __shared__ unsigned short tile[32][34];
    int isf32 = flags[flagIdx];
    size_t eoff = (size_t)blockIdx.z * R * C;
    const float* sf = (const float*)src + eoff;
    const unsigned short* sh = (const unsigned short*)src + eoff;
    dst += eoff;
    int c0 = blockIdx.x * 32, r0 = blockIdx.y * 32;
    int tx = threadIdx.x, ty = threadIdx.y;  // (32,8)
#pragma unroll
    for (int i = 0; i < 32; i += 8) {
        size_t si = (size_t)(r0 + ty + i) * C + (c0 + tx);
        tile[ty + i][tx] = isf32 ? f32_to_bf16_rne(sf[si]) : sh[si];
    }
    __syncthreads();
#pragma unroll
    for (int i = 0; i < 32; i += 8)
        dst[(size_t)(c0 + ty + i) * R + (r0 + tx)] = tile[tx][ty + i];
}

// ---------------- GEMM1: H = silu(X G) * (X U), dual accumulator, MFMA ----------------
// X: bf16 [NPAIR][HID] packed. Wg/Wu: bf16 [E][INTER][HID] (transposed, k-contig).
__global__ __launch_bounds__(256) void k_gemm1(
    const unsigned short* __restrict__ X,
    const unsigned short* __restrict__ Wg,
    const unsigned short* __restrict__ Wu,
    unsigned short* __restrict__ Hbuf,
    const int* __restrict__ counts, const int* __restrict__ offsets)
{
    const int e = blockIdx.z;
    const int cnt = counts[e];
    const int mt = blockIdx.x;
    if (mt * 128 >= cnt) return;
    const int off = offsets[e];
    const int nt0 = blockIdx.y * 128;

    __shared__ __align__(16) unsigned short sA [128 * 40];
    __shared__ __align__(16) unsigned short sBg[128 * 40];
    __shared__ __align__(16) unsigned short sBu[128 * 40];

    const int tid = threadIdx.x;
    const int wave = tid >> 6, lane = tid & 63;
    const int wm = (wave >> 1) * 64, wn = (wave & 1) * 64;
    const int q = lane >> 4, l15 = lane & 15;

    const int r0s = tid >> 2,         k0s = (tid & 3) << 3;
    const int r1s = (tid + 256) >> 2, k1s = ((tid + 256) & 3) << 3;

    int ga0 = off + mt * 128 + r0s; if (ga0 >= NPAIR) ga0 = NPAIR - 1;
    int ga1 = off + mt * 128 + r1s; if (ga1 >= NPAIR) ga1 = NPAIR - 1;
    const unsigned short* pA0 = X + (size_t)ga0 * HID + k0s;
    const unsigned short* pA1 = X + (size_t)ga1 * HID + k1s;
    const unsigned short* wgB = Wg + (size_t)e * INTER * HID;
    const unsigned short* wuB = Wu + (size_t)e * INTER * HID;
    const unsigned short* pG0 = wgB + (size_t)(nt0 + r0s) * HID + k0s;
    const unsigned short* pG1 = wgB + (size_t)(nt0 + r1s) * HID + k1s;
    const unsigned short* pU0 = wuB + (size_t)(nt0 + r0s) * HID + k0s;
    const unsigned short* pU1 = wuB + (size_t)(nt0 + r1s) * HID + k1s;

    floatx4 accg[4][4], accu[4][4];
#pragma unroll
    for (int i = 0; i < 4; ++i)
#pragma unroll
        for (int j = 0; j < 4; ++j)
#pragma unroll
            for (int r = 0; r < 4; ++r) { accg[i][j][r] = 0.f; accu[i][j][r] = 0.f; }

    for (int k0 = 0; k0 < HID; k0 += 32) {
        uint4 a0 = *(const uint4*)(pA0 + k0);
        uint4 a1 = *(const uint4*)(pA1 + k0);
        uint4 g0 = *(const uint4*)(pG0 + k0);
        uint4 g1 = *(const uint4*)(pG1 + k0);
        uint4 u0 = *(const uint4*)(pU0 + k0);
        uint4 u1 = *(const uint4*)(pU1 + k0);
        *(uint4*)(sA  + r0s * 40 + k0s) = a0;
        *(uint4*)(sA  + r1s * 40 + k1s) = a1;
        *(uint4*)(sBg + r0s * 40 + k0s) = g0;
        *(uint4*)(sBg + r1s * 40 + k1s) = g1;
        *(uint4*)(sBu + r0s * 40 + k0s) = u0;
        *(uint4*)(sBu + r1s * 40 + k1s) = u1;
        __syncthreads();
        short8 af[4], gf[4], uf[4];
#pragma unroll
        for (int i = 0; i < 4; ++i) {
            af[i] = *(const short8*)(sA  + (wm + i * 16 + l15) * 40 + q * 8);
            gf[i] = *(const short8*)(sBg + (wn + i * 16 + l15) * 40 + q * 8);
            uf[i] = *(const short8*)(sBu + (wn + i * 16 + l15) * 40 + q * 8);
        }
#pragma unroll
        for (int i = 0; i < 4; ++i)
#pragma unroll
            for (int j = 0; j < 4; ++j) {
                accg[i][j] = __builtin_amdgcn_mfma_f32_16x16x32_bf16(af[i], gf[j], accg[i][j], 0, 0, 0);
                accu[i][j] = __builtin_amdgcn_mfma_f32_16x16x32_bf16(af[i], uf[j], accu[i][j], 0, 0, 0);
            }
        __syncthreads();
    }

    // epilogue: silu(g)*u -> bf16. C/D layout: col=lane&15, row=quad*4+reg
#pragma unroll
    for (int i = 0; i < 4; ++i) {
#pragma unroll
        for (int r = 0; r < 4; ++r) {
            int rl = wm + i * 16 + q * 4 + r;
            int row = mt * 128 + rl;
            if (row < cnt) {
                unsigned short* hrow = Hbuf + (size_t)(off + row) * INTER + nt0;
#pragma unroll
                for (int j = 0; j < 4; ++j) {
                    float g = accg[i][j][r];
                    float u = accu[i][j][r];
                    float s = g / (1.0f + __expf(-g));
                    hrow[wn + j * 16 + l15] = f32_to_bf16_rne(s * u);
                }
            }
        }
    }
}

// ---------------- GEMM2: out[token] += w * (H Wd^T), fp32 atomics to d_out ----------------
__global__ __launch_bounds__(256) void k_gemm2(
    const unsigned short* __restrict__ Hbuf,
    const unsigned short* __restrict__ Wd,
    float* __restrict__ outf,
    const int* __restrict__ counts, const int* __restrict__ offsets,
    const int* __restrict__ perm_tok, const float* __restrict__ perm_w)
{
    const int e = blockIdx.z;
    const int cnt = counts[e];
    const int mt = blockIdx.x;
    if (mt * 128 >= cnt) return;
    const int off = offsets[e];
    const int nt0 = blockIdx.y * 128;

    __shared__ __align__(16) unsigned short sA[128 * 40];
    __shared__ __align__(16) unsigned short sB[128 * 40];

    const int tid = threadIdx.x;
    const int wave = tid >> 6, lane = tid & 63;
    const int wm = (wave >> 1) * 64, wn = (wave & 1) * 64;
    const int q = lane >> 4, l15 = lane & 15;

    const int r0s = tid >> 2,         k0s = (tid & 3) << 3;
    const int r1s = (tid + 256) >> 2, k1s = ((tid + 256) & 3) << 3;

    int ga0 = off + mt * 128 + r0s; if (ga0 >= NPAIR) ga0 = NPAIR - 1;
    int ga1 = off + mt * 128 + r1s; if (ga1 >= NPAIR) ga1 = NPAIR - 1;
    const unsigned short* pA0 = Hbuf + (size_t)ga0 * INTER + k0s;
    const unsigned short* pA1 = Hbuf + (size_t)ga1 * INTER + k1s;
    const unsigned short* wdB = Wd + (size_t)e * HID * INTER;
    const unsigned short* pB0 = wdB + (size_t)(nt0 + r0s) * INTER + k0s;
    const unsigned short* pB1 = wdB + (size_t)(nt0 + r1s) * INTER + k1s;

    floatx4 acc[4][4];
#pragma unroll
    for (int i = 0; i < 4; ++i)
#pragma unroll
        for (int j = 0; j < 4; ++j)
#pragma unroll
            for (int r = 0; r < 4; ++r) acc[i][j][r] = 0.f;

    for (int k0 = 0; k0 < INTER; k0 += 32) {
        uint4 a0 = *(const uint4*)(pA0 + k0);
        uint4 a1 = *(const uint4*)(pA1 + k0);
        uint4 b0 = *(const uint4*)(pB0 + k0);
        uint4 b1 = *(const uint4*)(pB1 + k0);
        *(uint4*)(sA + r0s * 40 + k0s) = a0;
        *(uint4*)(sA + r1s * 40 + k1s) = a1;
        *(uint4*)(sB + r0s * 40 + k0s) = b0;
        *(uint4*)(sB + r1s * 40 + k1s) = b1;
        __syncthreads();
        short8 af[4], bf[4];
#pragma unroll
        for (int i = 0; i < 4; ++i) {
            af[i] = *(const short8*)(sA + (wm + i * 16 + l15) * 40 + q * 8);
            bf[i] = *(const short8*)(sB + (wn + i * 16 + l15) * 40 + q * 8);
        }
#pragma unroll
        for (int i = 0; i < 4; ++i)
#pragma unroll
            for (int j = 0; j < 4; ++j)
                acc[i][j] = __builtin_amdgcn_mfma_f32_16x16x32_bf16(af[i], bf[j], acc[i][j], 0, 0, 0);
        __syncthreads();
    }

#pragma unroll
    for (int i = 0; i < 4; ++i) {
#pragma unroll
        for (int r = 0; r < 4; ++r) {
            int rl = wm + i * 16 + q * 4 + r;
            int row = mt * 128 + rl;
            if (row < cnt) {
                int gpos = off + row;
                int tok = perm_tok[gpos];
                float w = perm_w[gpos];
                float* orow = outf + (size_t)tok * HID + nt0;
#pragma unroll
                for (int j = 0; j < 4; ++j) {
#ifdef __HIP_PLATFORM_AMD__
                    unsafeAtomicAdd(&orow[wn + j * 16 + l15], w * acc[i][j][r]);
#else
                    atomicAdd(&orow[wn + j * 16 + l15], w * acc[i][j][r]);
#endif
                }
            }
        }
    }
}

extern "C" void kernel_launch(void* const* d_in, const int* in_sizes, int n_in,
                              void* d_out, int out_size, void* d_ws, size_t ws_size,
                              hipStream_t stream) {
    const void* tokens = d_in[0];
    const void* eidx   = d_in[1];
    const void* ew     = d_in[2];
    const void* gw     = d_in[3];
    const void* uw     = d_in[4];
    const void* dwp    = d_in[5];
    float* out = (float*)d_out;   // OUTPUT IS FP32 (R2/R3 forensics)
    char* ws = (char*)d_ws;

    if (ws_size < WS_NEEDED) {
        hipMemsetAsync(d_out, 0, (size_t)out_size * 4, stream);
        return;
    }

    int*   counts   = (int*)(ws + 0);
    int*   offsets  = (int*)(ws + 64);
    int*   fill     = (int*)(ws + 128);
    int*   flags    = (int*)(ws + 192);
    int*   perm_tok = (int*)(ws + O_PERMTOK);
    float* perm_w   = (float*)(ws + O_PERMW);
    unsigned short* X  = (unsigned short*)(ws + O_X);
    unsigned short* Wg = (unsigned short*)(ws + O_WG);
    unsigned short* Wu = (unsigned short*)(ws + O_WU);
    unsigned short* Wd = (unsigned short*)(ws + O_WD);
    unsigned short* Hb = (unsigned short*)(ws + O_HBUF);

    hipMemsetAsync(counts, 0, 256, stream);
    hipMemsetAsync(out, 0, (size_t)out_size * 4, stream);

    k_probe<<<1, 64, 0, stream>>>(tokens, ew, gw, uw, dwp, eidx, flags);
    k_route_count<<<NPAIR / 256, 256, 0, stream>>>((const int*)eidx, counts, flags);
    k_route_scan<<<1, 64, 0, stream>>>(counts, offsets, fill);
    k_route_fill<<<NPAIR / 256, 256, 0, stream>>>((const int*)eidx, ew, offsets, fill,
                                                  perm_tok, perm_w, flags);
    k_gather<<<NPAIR, 256, 0, stream>>>(tokens, perm_tok, X, flags);

    dim3 tb(32, 8);
    k_transpose<<<dim3(INTER / 32, HID / 32, NEXP), tb, 0, stream>>>(gw, Wg, HID, INTER, flags, 2);
    k_transpose<<<dim3(INTER / 32, HID / 32, NEXP), tb, 0, stream>>>(uw, Wu, HID, INTER, flags, 3);
    k_transpose<<<dim3(HID / 32, INTER / 32, NEXP), tb, 0, stream>>>(dwp, Wd, INTER, HID, flags, 4);

    k_gemm1<<<dim3(64, INTER / 128, NEXP), 256, 0, stream>>>(X, Wg, Wu, Hb, counts, offsets);
    k_gemm2<<<dim3(64, HID / 128, NEXP), 256, 0, stream>>>(Hb, Wd, out, counts, offsets,
                                                           perm_tok, perm_w);
}

// Round 5
// 911.794 us; speedup vs baseline: 1.2607x; 1.2607x over previous
//
#include <hip/hip_runtime.h>
#include <hip/hip_bf16.h>
#include <stdint.h>

#define NTOK  4096
#define TOPK  2
#define NEXP  8
#define HID   1024
#define INTER 2048
#define NPAIR (NTOK*TOPK)

typedef __attribute__((ext_vector_type(8))) short short8;
typedef __attribute__((ext_vector_type(4))) float floatx4;

#define AS1(p) ((const __attribute__((address_space(1))) void*)(p))
#define AS3(p) ((__attribute__((address_space(3))) void*)(p))

// ---------------- ws layout (bytes) ----------------
// ctrl @0: counts(8 int)@0, offsets@64, fill@128, flags@192 (6 int)
#define O_PERMTOK 4096ull
#define O_PERMW   (O_PERMTOK + (size_t)NPAIR*4)            // float[NPAIR]
#define O_X       (1ull<<20)                                // bf16 [NPAIR][HID]    16 MB
#define O_WG      (O_X  + (size_t)NPAIR*HID*2)              // bf16 [E][INTER][HID] 32 MB -> becomes Hbuf
#define O_WU      (O_WG + (size_t)NEXP*INTER*HID*2)         // bf16 [E][INTER][HID] 32 MB
#define O_WD      (O_WU + (size_t)NEXP*INTER*HID*2)         // bf16 [E][HID][INTER] 32 MB
#define O_GBUF    (O_WD + (size_t)NEXP*HID*INTER*2)         // bf16 [NPAIR][INTER]  32 MB
#define WS_NEEDED (O_GBUF + (size_t)NPAIR*INTER*2)
#define O_HBUF    O_WG   // Hbuf overlays Wg (Wg dead after k_g)

static __device__ __forceinline__ unsigned short f32_to_bf16_rne(float f) {
    union { float f; uint32_t u; } v; v.f = f;
    uint32_t b = v.u + 0x7fffu + ((v.u >> 16) & 1u);
    return (unsigned short)(b >> 16);
}
static __device__ __forceinline__ float bf16_to_f32(unsigned short u) {
    union { uint32_t i; float f; } cv; cv.i = ((uint32_t)u) << 16;
    return cv.f;
}

// ---------------- dtype probes ----------------
__global__ void k_probe(const void* __restrict__ tok, const void* __restrict__ ew,
                        const void* __restrict__ gw,  const void* __restrict__ uw,
                        const void* __restrict__ dw,  const void* __restrict__ eidx,
                        int* __restrict__ flags) {
    int lane = threadIdx.x;  // 64
    const void* ptrs[5] = { tok, ew, gw, uw, dw };
    for (int t = 0; t < 5; ++t) {
        const unsigned short* p = (const unsigned short*)ptrs[t];
        float v = bf16_to_f32(p[lane * 2]);
        unsigned long long m = __ballot(!(fabsf(v) < 1000.0f));
        if (lane == 0) flags[t] = (m != 0ull) ? 1 : 0;
    }
    const int* ix = (const int*)eidx;
    unsigned long long mi = __ballot(ix[lane * 2 + 1] != 0);
    if (lane == 0) flags[5] = (mi == 0ull) ? 1 : 0;
}

// ---------------- routing ----------------
__global__ void k_route_count(const int* __restrict__ idx, int* __restrict__ counts,
                              const int* __restrict__ flags) {
    int i64 = flags[5];
    int p = blockIdx.x * 256 + threadIdx.x;
    if (p < NPAIR) atomicAdd(&counts[idx[p << i64]], 1);
}

__global__ void k_route_scan(const int* __restrict__ counts, int* __restrict__ offsets,
                             int* __restrict__ fill) {
    if (threadIdx.x == 0) {
        int acc = 0;
        for (int e = 0; e < NEXP; ++e) { offsets[e] = acc; acc += counts[e]; fill[e] = 0; }
    }
}

__global__ void k_route_fill(const int* __restrict__ idx, const void* __restrict__ ew,
                             const int* __restrict__ offsets, int* __restrict__ fill,
                             int* __restrict__ perm_tok, float* __restrict__ perm_w,
                             const int* __restrict__ flags) {
    int ewf = flags[1], i64 = flags[5];
    int p = blockIdx.x * 256 + threadIdx.x;
    if (p < NPAIR) {
        int e = idx[p << i64];
        int pos = offsets[e] + atomicAdd(&fill[e], 1);
        perm_tok[pos] = p >> 1;
        perm_w[pos]   = ewf ? ((const float*)ew)[p]
                            : bf16_to_f32(((const unsigned short*)ew)[p]);
    }
}

// gather packed token rows -> bf16 X
__global__ void k_gather(const void* __restrict__ tokens, const int* __restrict__ perm_tok,
                         unsigned short* __restrict__ X, const int* __restrict__ flags) {
    int f = flags[0];
    int pos = blockIdx.x;
    int tok = perm_tok[pos];
    ushort4* d = (ushort4*)(X + (size_t)pos * HID);
    if (f) {
        float4 v = *(const float4*)((const float*)tokens + (size_t)tok * HID + threadIdx.x * 4);
        ushort4 o;
        o.x = f32_to_bf16_rne(v.x); o.y = f32_to_bf16_rne(v.y);
        o.z = f32_to_bf16_rne(v.z); o.w = f32_to_bf16_rne(v.w);
        d[threadIdx.x] = o;
    } else {
        d[threadIdx.x] = ((const ushort4*)((const unsigned short*)tokens + (size_t)tok * HID))[threadIdx.x];
    }
}

// transpose [R][C] -> bf16 [C][R] per expert (blockIdx.z)
__global__ void k_transpose(const void* __restrict__ src,
                            unsigned short* __restrict__ dst, int R, int C,
                            const int* __restrict__ flags, int flagIdx) {
    __shared__ unsigned short tile[32][34];
    int isf32 = flags[flagIdx];
    size_t eoff = (size_t)blockIdx.z * R * C;
    const float* sf = (const float*)src + eoff;
    const unsigned short* sh = (const unsigned short*)src + eoff;
    dst += eoff;
    int c0 = blockIdx.x * 32, r0 = blockIdx.y * 32;
    int tx = threadIdx.x, ty = threadIdx.y;  // (32,8)
#pragma unroll
    for (int i = 0; i < 32; i += 8) {
        size_t si = (size_t)(r0 + ty + i) * C + (c0 + tx);
        tile[ty + i][tx] = isf32 ? f32_to_bf16_rne(sf[si]) : sh[si];
    }
    __syncthreads();
#pragma unroll
    for (int i = 0; i < 32; i += 8)
        dst[(size_t)(c0 + ty + i) * R + (r0 + tx)] = tile[tx][ty + i];
}

// ---------------- m97-style MFMA core: 128x128 tile, BK=32, global_load_lds ----------------
// A: tile base (global bf16), row stride KHW halfwords, rows clamped to arowlim (tile-local)
// B: tile base, 128 full rows, stride KHW. LDS: sA/sB 128*32 halfwords, unpadded, XOR-swizzled.
template<int KHW>
__device__ __forceinline__ void mfma_core(
    const unsigned short* __restrict__ Ab, int arowlim,
    const unsigned short* __restrict__ Bb,
    unsigned short* sA, unsigned short* sB,
    int tid, floatx4 (&acc)[4][4])
{
    const int wave = tid >> 6, lane = tid & 63;
    const int sr = lane >> 2, sc = lane & 3;
    const int q = lane >> 4, l15 = lane & 15;
    const int wm = (wave >> 1) * 64, wn = (wave & 1) * 64;

    // staging geometry: wave stages rows [wave*32, wave*32+32) via 2 insts (16 rows each)
    const int r0 = wave * 32 + sr;
    const int r1 = r0 + 16;
    const int cs0 = sc ^ ((r0 >> 1) & 3);  // swizzled global chunk for LDS slot sc
    const int cs1 = sc ^ ((r1 >> 1) & 3);
    const int ar0 = min(r0, arowlim), ar1 = min(r1, arowlim);

    const char* gA0 = (const char*)(Ab + (size_t)ar0 * KHW) + cs0 * 16;
    const char* gA1 = (const char*)(Ab + (size_t)ar1 * KHW) + cs1 * 16;
    const char* gB0 = (const char*)(Bb + (size_t)r0 * KHW) + cs0 * 16;
    const char* gB1 = (const char*)(Bb + (size_t)r1 * KHW) + cs1 * 16;

    unsigned short* lA0 = sA + wave * 1024;   // 32 rows * 32 hw
    unsigned short* lA1 = lA0 + 512;
    unsigned short* lB0 = sB + wave * 1024;
    unsigned short* lB1 = lB0 + 512;

    const int aslot = (q ^ ((l15 >> 1) & 3)) * 8;  // frag k-slot (halfwords), swizzle-corrected

#pragma unroll 1
    for (int kk = 0; kk < KHW / 32; ++kk) {
        const int kb = kk * 64;  // 32 halfwords = 64 bytes per iter
        __builtin_amdgcn_global_load_lds(AS1(gA0 + kb), AS3(lA0), 16, 0, 0);
        __builtin_amdgcn_global_load_lds(AS1(gA1 + kb), AS3(lA1), 16, 0, 0);
        __builtin_amdgcn_global_load_lds(AS1(gB0 + kb), AS3(lB0), 16, 0, 0);
        __builtin_amdgcn_global_load_lds(AS1(gB1 + kb), AS3(lB1), 16, 0, 0);
        __syncthreads();
        short8 af[4], bfr[4];
#pragma unroll
        for (int i = 0; i < 4; ++i)
            af[i] = *(const short8*)(sA + (wm + i * 16 + l15) * 32 + aslot);
#pragma unroll
        for (int j = 0; j < 4; ++j)
            bfr[j] = *(const short8*)(sB + (wn + j * 16 + l15) * 32 + aslot);
#pragma unroll
        for (int i = 0; i < 4; ++i)
#pragma unroll
            for (int j = 0; j < 4; ++j)
                acc[i][j] = __builtin_amdgcn_mfma_f32_16x16x32_bf16(af[i], bfr[j], acc[i][j], 0, 0, 0);
        __syncthreads();
    }
}

// ---------------- k_g: Gbuf = X * Wg^T ----------------
__global__ __launch_bounds__(256) void k_g(
    const unsigned short* __restrict__ X, const unsigned short* __restrict__ Wg,
    unsigned short* __restrict__ Gbuf,
    const int* __restrict__ counts, const int* __restrict__ offsets)
{
    const int e = blockIdx.z, cnt = counts[e], mt = blockIdx.x;
    if (mt * 128 >= cnt) return;
    const int off = offsets[e], nt0 = blockIdx.y * 128;

    __shared__ __align__(16) unsigned short sA[128 * 32];
    __shared__ __align__(16) unsigned short sB[128 * 32];

    const int tid = threadIdx.x;
    const int wave = tid >> 6, lane = tid & 63;
    const int wm = (wave >> 1) * 64, wn = (wave & 1) * 64;
    const int q = lane >> 4, l15 = lane & 15;

    floatx4 acc[4][4];
#pragma unroll
    for (int i = 0; i < 4; ++i)
#pragma unroll
        for (int j = 0; j < 4; ++j)
#pragma unroll
            for (int r = 0; r < 4; ++r) acc[i][j][r] = 0.f;

    mfma_core<HID>(X + (size_t)(off + mt * 128) * HID, NPAIR - 1 - (off + mt * 128),
                   Wg + (size_t)e * INTER * HID + (size_t)nt0 * HID, sA, sB, tid, acc);

#pragma unroll
    for (int i = 0; i < 4; ++i)
#pragma unroll
        for (int r = 0; r < 4; ++r) {
            int row = mt * 128 + wm + i * 16 + q * 4 + r;
            if (row < cnt) {
                unsigned short* grow = Gbuf + (size_t)(off + row) * INTER + nt0;
#pragma unroll
                for (int j = 0; j < 4; ++j)
                    grow[wn + j * 16 + l15] = f32_to_bf16_rne(acc[i][j][r]);
            }
        }
}

// ---------------- k_u: Hbuf = silu(Gbuf) * (X * Wu^T) ----------------
__global__ __launch_bounds__(256) void k_u(
    const unsigned short* __restrict__ X, const unsigned short* __restrict__ Wu,
    const unsigned short* __restrict__ Gbuf, unsigned short* __restrict__ Hbuf,
    const int* __restrict__ counts, const int* __restrict__ offsets)
{
    const int e = blockIdx.z, cnt = counts[e], mt = blockIdx.x;
    if (mt * 128 >= cnt) return;
    const int off = offsets[e], nt0 = blockIdx.y * 128;

    __shared__ __align__(16) unsigned short sA[128 * 32];
    __shared__ __align__(16) unsigned short sB[128 * 32];

    const int tid = threadIdx.x;
    const int wave = tid >> 6, lane = tid & 63;
    const int wm = (wave >> 1) * 64, wn = (wave & 1) * 64;
    const int q = lane >> 4, l15 = lane & 15;

    floatx4 acc[4][4];
#pragma unroll
    for (int i = 0; i < 4; ++i)
#pragma unroll
        for (int j = 0; j < 4; ++j)
#pragma unroll
            for (int r = 0; r < 4; ++r) acc[i][j][r] = 0.f;

    mfma_core<HID>(X + (size_t)(off + mt * 128) * HID, NPAIR - 1 - (off + mt * 128),
                   Wu + (size_t)e * INTER * HID + (size_t)nt0 * HID, sA, sB, tid, acc);

#pragma unroll
    for (int i = 0; i < 4; ++i)
#pragma unroll
        for (int r = 0; r < 4; ++r) {
            int row = mt * 128 + wm + i * 16 + q * 4 + r;
            if (row < cnt) {
                const unsigned short* grow = Gbuf + (size_t)(off + row) * INTER + nt0;
                unsigned short* hrow = Hbuf + (size_t)(off + row) * INTER + nt0;
#pragma unroll
                for (int j = 0; j < 4; ++j) {
                    float g = bf16_to_f32(grow[wn + j * 16 + l15]);
                    float s = g / (1.0f + __expf(-g));
                    hrow[wn + j * 16 + l15] = f32_to_bf16_rne(s * acc[i][j][r]);
                }
            }
        }
}

// ---------------- k_d: out[token] += w * (Hbuf * Wd^T) ----------------
__global__ __launch_bounds__(256) void k_d(
    const unsigned short* __restrict__ Hbuf, const unsigned short* __restrict__ Wd,
    float* __restrict__ outf,
    const int* __restrict__ counts, const int* __restrict__ offsets,
    const int* __restrict__ perm_tok, const float* __restrict__ perm_w)
{
    const int e = blockIdx.z, cnt = counts[e], mt = blockIdx.x;
    if (mt * 128 >= cnt) return;
    const int off = offsets[e], nt0 = blockIdx.y * 128;

    __shared__ __align__(16) unsigned short sA[128 * 32];
    __shared__ __align__(16) unsigned short sB[128 * 32];

    const int tid = threadIdx.x;
    const int wave = tid >> 6, lane = tid & 63;
    const int wm = (wave >> 1) * 64, wn = (wave & 1) * 64;
    const int q = lane >> 4, l15 = lane & 15;

    floatx4 acc[4][4];
#pragma unroll
    for (int i = 0; i < 4; ++i)
#pragma unroll
        for (int j = 0; j < 4; ++j)
#pragma unroll
            for (int r = 0; r < 4; ++r) acc[i][j][r] = 0.f;

    mfma_core<INTER>(Hbuf + (size_t)(off + mt * 128) * INTER, NPAIR - 1 - (off + mt * 128),
                     Wd + (size_t)e * HID * INTER + (size_t)nt0 * INTER, sA, sB, tid, acc);

#pragma unroll
    for (int i = 0; i < 4; ++i)
#pragma unroll
        for (int r = 0; r < 4; ++r) {
            int row = mt * 128 + wm + i * 16 + q * 4 + r;
            if (row < cnt) {
                int gpos = off + row;
                int tok = perm_tok[gpos];
                float w = perm_w[gpos];
                float* orow = outf + (size_t)tok * HID + nt0;
#pragma unroll
                for (int j = 0; j < 4; ++j) {
#ifdef __HIP_PLATFORM_AMD__
                    unsafeAtomicAdd(&orow[wn + j * 16 + l15], w * acc[i][j][r]);
#else
                    atomicAdd(&orow[wn + j * 16 + l15], w * acc[i][j][r]);
#endif
                }
            }
        }
}

extern "C" void kernel_launch(void* const* d_in, const int* in_sizes, int n_in,
                              void* d_out, int out_size, void* d_ws, size_t ws_size,
                              hipStream_t stream) {
    const void* tokens = d_in[0];
    const void* eidx   = d_in[1];
    const void* ew     = d_in[2];
    const void* gw     = d_in[3];
    const void* uw     = d_in[4];
    const void* dwp    = d_in[5];
    float* out = (float*)d_out;   // fp32 output (R2/R3 forensics)
    char* ws = (char*)d_ws;

    if (ws_size < WS_NEEDED) {
        hipMemsetAsync(d_out, 0, (size_t)out_size * 4, stream);
        return;
    }

    int*   counts   = (int*)(ws + 0);
    int*   offsets  = (int*)(ws + 64);
    int*   fill     = (int*)(ws + 128);
    int*   flags    = (int*)(ws + 192);
    int*   perm_tok = (int*)(ws + O_PERMTOK);
    float* perm_w   = (float*)(ws + O_PERMW);
    unsigned short* X  = (unsigned short*)(ws + O_X);
    unsigned short* Wg = (unsigned short*)(ws + O_WG);
    unsigned short* Wu = (unsigned short*)(ws + O_WU);
    unsigned short* Wd = (unsigned short*)(ws + O_WD);
    unsigned short* Gb = (unsigned short*)(ws + O_GBUF);
    unsigned short* Hb = (unsigned short*)(ws + O_HBUF);  // overlays Wg

    hipMemsetAsync(counts, 0, 256, stream);
    hipMemsetAsync(out, 0, (size_t)out_size * 4, stream);

    k_probe<<<1, 64, 0, stream>>>(tokens, ew, gw, uw, dwp, eidx, flags);
    k_route_count<<<NPAIR / 256, 256, 0, stream>>>((const int*)eidx, counts, flags);
    k_route_scan<<<1, 64, 0, stream>>>(counts, offsets, fill);
    k_route_fill<<<NPAIR / 256, 256, 0, stream>>>((const int*)eidx, ew, offsets, fill,
                                                  perm_tok, perm_w, flags);
    k_gather<<<NPAIR, 256, 0, stream>>>(tokens, perm_tok, X, flags);

    dim3 tb(32, 8);
    k_transpose<<<dim3(INTER / 32, HID / 32, NEXP), tb, 0, stream>>>(gw, Wg, HID, INTER, flags, 2);
    k_transpose<<<dim3(INTER / 32, HID / 32, NEXP), tb, 0, stream>>>(uw, Wu, HID, INTER, flags, 3);
    k_transpose<<<dim3(HID / 32, INTER / 32, NEXP), tb, 0, stream>>>(dwp, Wd, INTER, HID, flags, 4);

    k_g<<<dim3(64, INTER / 128, NEXP), 256, 0, stream>>>(X, Wg, Gb, counts, offsets);
    k_u<<<dim3(64, INTER / 128, NEXP), 256, 0, stream>>>(X, Wu, Gb, Hb, counts, offsets);
    k_d<<<dim3(64, HID / 128, NEXP), 256, 0, stream>>>(Hb, Wd, out, counts, offsets,
                                                       perm_tok, perm_w);
}